// Round 3
// baseline (1797.082 us; speedup 1.0000x reference)
//
#include <hip/hip_runtime.h>
#include <hip/hip_bf16.h>
#include <stdint.h>

#define W4   20736           // 12^4 positions (w == W4, no padding)
#define NH   8
#define KD   32
#define HD   64
#define C    512
#define SCALE 0.17677669529663687f   // 1/sqrt(32)

typedef unsigned long long ull;
typedef short bf16x8 __attribute__((ext_vector_type(8)));
typedef _Float16 f16x8 __attribute__((ext_vector_type(8)));
typedef float f32x4 __attribute__((ext_vector_type(4)));

#define AS1(p) ((const __attribute__((address_space(1))) void*)(p))
#define AS3(p) ((__attribute__((address_space(3))) void*)(p))

// Manual RNE fp32 -> bf16 (no NaN handling needed; values finite)
static __device__ __forceinline__ unsigned short f2bf(float v) {
    unsigned u = __builtin_bit_cast(unsigned, v);
    unsigned r = u + 0x7FFF + ((u >> 16) & 1);
    return (unsigned short)(r >> 16);
}
static __device__ __forceinline__ float bf2f(unsigned short u) {
    unsigned x = ((unsigned)u) << 16;
    return __builtin_bit_cast(float, x);
}
// fp32 -> fp16 bits (RNE via v_cvt_f16_f32)
static __device__ __forceinline__ unsigned short f2h(float v) {
    return __builtin_bit_cast(unsigned short, (_Float16)v);
}

// ---------------------------------------------------------------------------
// prep1: fold head-summed K weights (fp32); build epilogue routing tables.
// ---------------------------------------------------------------------------
__global__ __launch_bounds__(256) void prep1_kernel(
    const float* qk1_w, const float* qk1_g, const float* qk1_b,
    const float* qk2_w, const float* qk2_g, const float* qk2_b,
    const float* v_b,   const float* proj_b,
    float* ksw1, float* ksw2,
    ull* opA, int* bsA, float* biasA,
    ull* opP, int* bsP, float* biasP,
    float* q1buf, float* q2buf, float* ks1buf, float* ks2buf, float* vdst)
{
    int z = blockIdx.x, t = threadIdx.x;
    if (z < 32) {                       // ksw1 row d=z : sum_h g*W over k1 channels
        int d = z;
        for (int c = t; c < 512; c += 256) {
            float a = 0.f;
            #pragma unroll
            for (int h = 0; h < 8; h++) {
                int ch = h * 64 + 32 + d;
                a += qk1_g[ch] * qk1_w[ch * 512 + c];
            }
            ksw1[d * 512 + c] = a;
        }
    } else if (z < 64) {                // ksw2 row d=z-32
        int d = z - 32;
        for (int c = t; c < 512; c += 256) {
            float a = 0.f;
            #pragma unroll
            for (int h = 0; h < 8; h++) {
                int ch = h * 64 + 32 + d;
                a += qk2_g[ch] * qk2_w[ch * 512 + c];
            }
            ksw2[d * 512 + c] = a;
        }
    } else if (z == 64) {               // table A: 1152 rows (1088 valid)
        for (int o = t; o < 1152; o += 256) {
            ull op; int bs; float bb;
            if (o < 256) {
                int ch = (o >> 5) * 64 + (o & 31);
                bb = qk1_b[ch];
                op = (ull)(uintptr_t)(q1buf + (size_t)o * W4); bs = 256 * W4;
            } else if (o < 512) {
                int oo = o - 256, ch = (oo >> 5) * 64 + (oo & 31);
                bb = qk2_b[ch];
                op = (ull)(uintptr_t)(q2buf + (size_t)oo * W4); bs = 256 * W4;
            } else if (o < 1024) {
                int c = o - 512;
                bb = v_b[c];
                op = (ull)(uintptr_t)(vdst + (size_t)c * W4); bs = 512 * W4;
            } else if (o < 1056) {
                int d = o - 1024; bb = 0.f;
                #pragma unroll
                for (int h = 0; h < 8; h++) bb += qk1_b[h * 64 + 32 + d];
                op = (ull)(uintptr_t)(ks1buf + (size_t)d * W4); bs = 32 * W4;
            } else if (o < 1088) {
                int d = o - 1056; bb = 0.f;
                #pragma unroll
                for (int h = 0; h < 8; h++) bb += qk2_b[h * 64 + 32 + d];
                op = (ull)(uintptr_t)(ks2buf + (size_t)d * W4); bs = 32 * W4;
            } else {                    // pad (masked by m_valid in epilogue)
                bb = 0.f; op = (ull)(uintptr_t)q1buf; bs = 0;
            }
            opA[o] = op; bsA[o] = bs; biasA[o] = bb;
        }
    } else {                            // table P (proj, 512 rows)
        for (int o = t; o < 512; o += 256) {
            opP[o] = (ull)(uintptr_t)(vdst + (size_t)o * W4);
            bsP[o] = 512 * W4;
            biasP[o] = proj_b[o];
        }
    }
}

// ---------------------------------------------------------------------------
// prep2: rows 0..1151 -> Waf fp16 (q1|q2|v|ks1|ks2|pad0, g folded);
// rows 1152..1663 -> Wph/Wpl bf16 hi/lo split (proj, exact path).
// ---------------------------------------------------------------------------
__global__ __launch_bounds__(256) void prep2_kernel(
    const float* qk1_w, const float* qk1_g,
    const float* qk2_w, const float* qk2_g,
    const float* v_w,   const float* v_g,
    const float* proj_w,const float* proj_g,
    const float* ksw1,  const float* ksw2,
    unsigned short* Waf,
    unsigned short* Wph, unsigned short* Wpl)
{
    int row = blockIdx.x, t = threadIdx.x;
    for (int c = t; c < 512; c += 256) {
        float wv;
        if (row < 1152) {
            int o = row;
            if (o < 256) {
                int ch = (o >> 5) * 64 + (o & 31);
                wv = qk1_w[ch * 512 + c] * qk1_g[ch];
            } else if (o < 512) {
                int oo = o - 256, ch = (oo >> 5) * 64 + (oo & 31);
                wv = qk2_w[ch * 512 + c] * qk2_g[ch];
            } else if (o < 1024) {
                int cc = o - 512;
                wv = v_w[cc * 512 + c] * v_g[cc];
            } else if (o < 1056) {
                wv = ksw1[(o - 1024) * 512 + c];
            } else if (o < 1088) {
                wv = ksw2[(o - 1056) * 512 + c];
            } else wv = 0.f;
            Waf[o * 512 + c] = f2h(wv);
        } else {
            int o = row - 1152;
            wv = proj_w[o * 512 + c] * proj_g[o];
            unsigned short h = f2bf(wv);
            Wph[o * 512 + c] = h;
            Wpl[o * 512 + c] = f2bf(wv - bf2f(h));
        }
    }
}

// ---------------------------------------------------------------------------
// castTf16: fp32 [b][512][W4] -> fp16 [b][W4][512] (transposed, single plane).
// 32x32 LDS tile transpose. Grid (648, 16, 4), block 256.
// ---------------------------------------------------------------------------
__global__ __launch_bounds__(256) void castTf16_kernel(
    const float* __restrict__ in, unsigned short* __restrict__ of)
{
    __shared__ float tile[32][33];
    const int p0 = blockIdx.x * 32, c0 = blockIdx.y * 32, b = blockIdx.z;
    const int tx = threadIdx.x & 31, ty = threadIdx.x >> 5;
    const float* ip = in + ((long)b * 512 + c0) * W4 + p0;
    #pragma unroll
    for (int r = 0; r < 4; r++)
        tile[ty + r * 8][tx] = ip[(long)(ty + r * 8) * W4 + tx];
    __syncthreads();
    unsigned short* ofp = of + ((long)b * W4 + p0) * 512 + c0;
    #pragma unroll
    for (int r = 0; r < 4; r++)
        ofp[(long)(ty + r * 8) * 512 + tx] = f2h(tile[tx][ty + r * 8]);
}

// ---------------------------------------------------------------------------
// mfma_gemm_f16: out[o,p] = A[o,:]·B[p,:] + bias[o], single fp16 MFMA.
// 128x128 tile, BK=32, 4 waves, 16x16x32 MFMA, m97 staging, XCD-chunk swizzle.
// ---------------------------------------------------------------------------
__global__ __launch_bounds__(256, 2) void mfma_gemm_f16(
    const unsigned short* __restrict__ Af,
    const unsigned short* __restrict__ Bf,
    const ull* __restrict__ outp, const int* __restrict__ obstr,
    const float* __restrict__ btab, int m_valid)
{
    __shared__ __align__(16) unsigned short sA[4096], sB[4096];
    const int t = threadIdx.x;
    const unsigned nx = gridDim.x, ny = gridDim.y;
    unsigned flat = blockIdx.x + nx * (blockIdx.y + ny * blockIdx.z);
    const unsigned cpx = (nx * ny * gridDim.z) >> 3;
    flat = (flat & 7u) * cpx + (flat >> 3);
    const int m0 = (int)(flat % nx) * 128;
    const int p0 = (int)((flat / nx) % ny) * 128;
    const int b  = (int)(flat / (nx * ny));
    const int lane = t & 63, wid = t >> 6;
    const int wm = wid >> 1, wn = wid & 1;
    const int r0 = t >> 2, part = (t & 3) * 8;
    const unsigned short* gA = Af + (size_t)(m0 + r0) * 512 + part;
    const unsigned short* gB = Bf + ((size_t)b * W4 + p0 + r0) * 512 + part;

    f32x4 acc[4][4];
    #pragma unroll
    for (int i = 0; i < 4; i++)
        #pragma unroll
        for (int j = 0; j < 4; j++) acc[i][j] = (f32x4)(0.f);

    const int arow = wm * 64 + (lane & 15);
    const int brow = wn * 64 + (lane & 15);
    const int koff = (lane >> 4) * 8;

    for (int k0 = 0; k0 < 512; k0 += 32) {
        __builtin_amdgcn_global_load_lds(AS1(gA + k0),          AS3((char*)sA + t * 16),        16, 0, 0);
        __builtin_amdgcn_global_load_lds(AS1(gA + 32768 + k0),  AS3((char*)sA + t * 16 + 4096), 16, 0, 0);
        __builtin_amdgcn_global_load_lds(AS1(gB + k0),          AS3((char*)sB + t * 16),        16, 0, 0);
        __builtin_amdgcn_global_load_lds(AS1(gB + 32768 + k0),  AS3((char*)sB + t * 16 + 4096), 16, 0, 0);
        __syncthreads();
        f16x8 a[4], bb[4];
        #pragma unroll
        for (int f = 0; f < 4; f++) {
            a[f]  = *(const f16x8*)(sA + (arow + f * 16) * 32 + koff);
            bb[f] = *(const f16x8*)(sB + (brow + f * 16) * 32 + koff);
        }
        #pragma unroll
        for (int i = 0; i < 4; i++)
            #pragma unroll
            for (int j = 0; j < 4; j++)
                acc[i][j] = __builtin_amdgcn_mfma_f32_16x16x32_f16(a[i], bb[j], acc[i][j], 0, 0, 0);
        __syncthreads();
    }
    const int quad = lane >> 4, col = lane & 15;
    #pragma unroll
    for (int i = 0; i < 4; i++) {
        #pragma unroll
        for (int r = 0; r < 4; r++) {
            int o = m0 + wm * 64 + i * 16 + quad * 4 + r;
            if (o >= m_valid) continue;
            float bias = btab[o];
            float* op = (float*)(uintptr_t)outp[o] + (long)b * obstr[o] + p0 + wn * 64 + col;
            #pragma unroll
            for (int j = 0; j < 4; j++)
                op[j * 16] = acc[i][j][r] + bias;
        }
    }
}

// ---------------------------------------------------------------------------
// mfma_gemm: split-bf16 (3 MFMA / tile) — kept for the proj GEMM (exact path).
// ---------------------------------------------------------------------------
__global__ __launch_bounds__(256, 2) void mfma_gemm(
    const unsigned short* __restrict__ Ah, const unsigned short* __restrict__ Al,
    const unsigned short* __restrict__ Bh, const unsigned short* __restrict__ Bl,
    const ull* __restrict__ outp, const int* __restrict__ obstr,
    const float* __restrict__ btab, int m_valid)
{
    __shared__ __align__(16) unsigned short sAh[4096], sAl[4096], sBh[4096], sBl[4096];
    const int t = threadIdx.x;
    const unsigned nx = gridDim.x, ny = gridDim.y;
    unsigned flat = blockIdx.x + nx * (blockIdx.y + ny * blockIdx.z);
    const unsigned cpx = (nx * ny * gridDim.z) >> 3;
    flat = (flat & 7u) * cpx + (flat >> 3);
    const int m0 = (int)(flat % nx) * 128;
    const int p0 = (int)((flat / nx) % ny) * 128;
    const int b  = (int)(flat / (nx * ny));
    const int lane = t & 63, wid = t >> 6;
    const int wm = wid >> 1, wn = wid & 1;
    const int r0 = t >> 2, part = (t & 3) * 8;
    const unsigned short* gAh = Ah + (size_t)(m0 + r0) * 512 + part;
    const unsigned short* gAl = Al + (size_t)(m0 + r0) * 512 + part;
    const unsigned short* gBh = Bh + ((size_t)b * W4 + p0 + r0) * 512 + part;
    const unsigned short* gBl = Bl + ((size_t)b * W4 + p0 + r0) * 512 + part;

    f32x4 acc[4][4];
    #pragma unroll
    for (int i = 0; i < 4; i++)
        #pragma unroll
        for (int j = 0; j < 4; j++) acc[i][j] = (f32x4)(0.f);

    const int arow = wm * 64 + (lane & 15);
    const int brow = wn * 64 + (lane & 15);
    const int koff = (lane >> 4) * 8;

    for (int k0 = 0; k0 < 512; k0 += 32) {
        __builtin_amdgcn_global_load_lds(AS1(gAh + k0),          AS3((char*)sAh + t * 16),        16, 0, 0);
        __builtin_amdgcn_global_load_lds(AS1(gAh + 32768 + k0),  AS3((char*)sAh + t * 16 + 4096), 16, 0, 0);
        __builtin_amdgcn_global_load_lds(AS1(gAl + k0),          AS3((char*)sAl + t * 16),        16, 0, 0);
        __builtin_amdgcn_global_load_lds(AS1(gAl + 32768 + k0),  AS3((char*)sAl + t * 16 + 4096), 16, 0, 0);
        __builtin_amdgcn_global_load_lds(AS1(gBh + k0),          AS3((char*)sBh + t * 16),        16, 0, 0);
        __builtin_amdgcn_global_load_lds(AS1(gBh + 32768 + k0),  AS3((char*)sBh + t * 16 + 4096), 16, 0, 0);
        __builtin_amdgcn_global_load_lds(AS1(gBl + k0),          AS3((char*)sBl + t * 16),        16, 0, 0);
        __builtin_amdgcn_global_load_lds(AS1(gBl + 32768 + k0),  AS3((char*)sBl + t * 16 + 4096), 16, 0, 0);
        __syncthreads();
        bf16x8 ah[4], al[4], bh[4], bl[4];
        #pragma unroll
        for (int f = 0; f < 4; f++) {
            ah[f] = *(const bf16x8*)(sAh + (arow + f * 16) * 32 + koff);
            al[f] = *(const bf16x8*)(sAl + (arow + f * 16) * 32 + koff);
            bh[f] = *(const bf16x8*)(sBh + (brow + f * 16) * 32 + koff);
            bl[f] = *(const bf16x8*)(sBl + (brow + f * 16) * 32 + koff);
        }
        #pragma unroll
        for (int i = 0; i < 4; i++)
            #pragma unroll
            for (int j = 0; j < 4; j++) {
                acc[i][j] = __builtin_amdgcn_mfma_f32_16x16x32_bf16(ah[i], bh[j], acc[i][j], 0, 0, 0);
                acc[i][j] = __builtin_amdgcn_mfma_f32_16x16x32_bf16(ah[i], bl[j], acc[i][j], 0, 0, 0);
                acc[i][j] = __builtin_amdgcn_mfma_f32_16x16x32_bf16(al[i], bh[j], acc[i][j], 0, 0, 0);
            }
        __syncthreads();
    }
    const int quad = lane >> 4, col = lane & 15;
    #pragma unroll
    for (int i = 0; i < 4; i++) {
        #pragma unroll
        for (int r = 0; r < 4; r++) {
            int o = m0 + wm * 64 + i * 16 + quad * 4 + r;
            if (o >= m_valid) continue;
            float bias = btab[o];
            float* op = (float*)(uintptr_t)outp[o] + (long)b * obstr[o] + p0 + wn * 64 + col;
            #pragma unroll
            for (int j = 0; j < 4; j++)
                op[j * 16] = acc[i][j][r] + bias;
        }
    }
}

// ---------------------------------------------------------------------------
// logits12: all 12 T per thread (q read once).
// ---------------------------------------------------------------------------
__global__ __launch_bounds__(256) void logits12_kernel(
    const float* __restrict__ q, const float* __restrict__ ks,
    float* __restrict__ w, int stride)
{
    const int bh = blockIdx.y, b = bh >> 3, H = bh & 7;
    const int p = blockIdx.x * 256 + threadIdx.x;
    const int ip = (p / stride) % 12;
    const float* qp = q + ((long)(b * 256 + H * 32)) * W4 + p;
    const float* kp = ks + ((long)(b * 32)) * W4 + p - (long)ip * stride;
    float acc[12];
    #pragma unroll
    for (int T = 0; T < 12; T++) acc[T] = 0.f;
    for (int d = 0; d < 32; d++) {
        float qv = qp[(long)d * W4];
        #pragma unroll
        for (int T = 0; T < 12; T++)
            acc[T] += qv * kp[(long)d * W4 + (long)T * stride];
    }
    #pragma unroll
    for (int T = 0; T < 12; T++)
        w[((long)bh * 12 + T) * W4 + p] = acc[T] * SCALE;
}

// ---------------------------------------------------------------------------
// logits3: w2 (stride 144), w3 (stride 12), w4 (stride 1) in ONE pass over q2.
// ---------------------------------------------------------------------------
__global__ __launch_bounds__(256) void logits3_kernel(
    const float* __restrict__ q, const float* __restrict__ ks,
    float* __restrict__ w2, float* __restrict__ w3, float* __restrict__ w4)
{
    const int bh = blockIdx.y, b = bh >> 3, H = bh & 7;
    const int p = blockIdx.x * 256 + threadIdx.x;
    const int i2 = (p / 144) % 12, i3 = (p / 12) % 12, i4 = p % 12;
    const float* qp = q + ((long)(b * 256 + H * 32)) * W4 + p;
    const float* kb = ks + ((long)(b * 32)) * W4 + p;
    const float* k2 = kb - i2 * 144;
    const float* k3 = kb - i3 * 12;
    const float* k4 = kb - i4;
    float a2[12], a3[12], a4[12];
    #pragma unroll
    for (int T = 0; T < 12; T++) { a2[T] = 0.f; a3[T] = 0.f; a4[T] = 0.f; }
    for (int d = 0; d < 32; d++) {
        const long o = (long)d * W4;
        float qv = qp[o];
        #pragma unroll
        for (int T = 0; T < 12; T++) {
            a2[T] += qv * k2[o + T * 144];
            a3[T] += qv * k3[o + T * 12];
            a4[T] += qv * k4[o + T];
        }
    }
    #pragma unroll
    for (int T = 0; T < 12; T++) {
        const long wo = ((long)bh * 12 + T) * W4 + p;
        w2[wo] = a2[T] * SCALE;
        w3[wo] = a3[T] * SCALE;
        w4[wo] = a4[T] * SCALE;
    }
}

// softmax over the `stride` axis (12 entries) — verified round 2
__global__ __launch_bounds__(256) void softmax_kernel(float* w, int stride)
{
    const int bh = blockIdx.z, T = blockIdx.y;
    const int r = blockIdx.x * 256 + threadIdx.x;
    if (r >= 1728) return;
    const long base = ((long)bh * 12 + T) * W4
                    + (long)(r / stride) * (stride * 12) + (r % stride);
    float v[12], m = -1e30f;
    #pragma unroll
    for (int s = 0; s < 12; s++) { v[s] = w[base + (long)s * stride]; m = fmaxf(m, v[s]); }
    float sum = 0.f;
    #pragma unroll
    for (int s = 0; s < 12; s++) { v[s] = __expf(v[s] - m); sum += v[s]; }
    const float inv = 1.f / sum;
    #pragma unroll
    for (int s = 0; s < 12; s++) w[base + (long)s * stride] = v[s] * inv;
}

// ---------------------------------------------------------------------------
// apply12: all 12 outputs along the contraction axis per thread.
// Thread owns intra-period offset (g,u): p_base = g*12*stride + u.
//   out[row, p_base + T*stride] = sum_s in[row, p_base + s*stride]
//                               * w[bh, T, p_base + s*stride]
// in-values register-cached (read HBM exactly once); w block L2-reused by the
// 64 channels of each head. Bit-identical accumulation order vs apply_kernel.
// Grid (9, 2048), block 192 (1728 offsets per row).
// ---------------------------------------------------------------------------
__global__ __launch_bounds__(192) void apply12_kernel(
    const float* __restrict__ in, const float* __restrict__ w,
    float* __restrict__ out, int stride)
{
    const long row = blockIdx.y;
    const int  b = (int)(row >> 9), c = (int)(row & 511), H = c >> 6;
    const int  idx = blockIdx.x * 192 + threadIdx.x;     // [0, 1728)
    const int  g = idx / stride;                          // 0 when stride==1728
    const int  u = idx - g * stride;
    const long pbase = (long)g * stride * 12 + u;
    const float* ip = in + row * W4 + pbase;
    const float* wp = w + ((long)(b * 8 + H) * 12) * W4 + pbase;
    float* op = out + row * W4 + pbase;
    float vin[12];
    #pragma unroll
    for (int s = 0; s < 12; s++) vin[s] = ip[(long)s * stride];
    #pragma unroll
    for (int T = 0; T < 12; T++) {
        const float* wT = wp + (long)T * W4;
        float acc = 0.f;
        #pragma unroll
        for (int s = 0; s < 12; s++)
            acc += vin[s] * wT[(long)s * stride];
        op[(long)T * stride] = acc;
    }
}

// ---------------------------------------------------------------------------
// mbuild12: all 12 X per thread; w3 K-column register-cached (read once).
//   M[bh,X,p] = sum_K w3[bh,K,p] * w4[bh,X, p-kp*12 + K*12],  kp=(p/12)%12
// Grid (81, 32), block 256. Bit-identical accumulation order vs mbuild.
// ---------------------------------------------------------------------------
__global__ __launch_bounds__(256) void mbuild12_kernel(
    const float* __restrict__ w3, const float* __restrict__ w4,
    float* __restrict__ Mw)
{
    const int bh = blockIdx.y;
    const int p = blockIdx.x * 256 + threadIdx.x;
    const int kp = (p / 12) % 12;
    const long b3 = ((long)bh * 12) * W4 + p;
    float v3[12];
    #pragma unroll
    for (int K = 0; K < 12; K++) v3[K] = w3[b3 + (long)K * W4];
    const long b4r = ((long)bh * 12) * W4 + p - kp * 12;
    #pragma unroll
    for (int X = 0; X < 12; X++) {
        const float* w4X = w4 + b4r + (long)X * W4;
        float acc = 0.f;
        #pragma unroll
        for (int K = 0; K < 12; K++)
            acc += v3[K] * w4X[K * 12];
        Mw[((long)bh * 12 + X) * W4 + p] = acc;
    }
}

// ---------------------------------------------------------------------------
// fuse_y: y = (A2 ⊗ M) + pe(v0) -> transposed bf16 hi/lo planes (proj input).
// ---------------------------------------------------------------------------
__global__ __launch_bounds__(256) void fuse_y_kernel(
    const float* __restrict__ A2, const float* __restrict__ Mw,
    const float* __restrict__ v0,
    const float* __restrict__ pw, const float* __restrict__ pg,
    const float* __restrict__ pb,
    unsigned short* __restrict__ oh, unsigned short* __restrict__ ol)
{
    __shared__ float tile[32][33];
    const int p0 = blockIdx.x * 32, c0 = blockIdx.y * 32, b = blockIdx.z;
    const int tx = threadIdx.x & 31, ty = threadIdx.x >> 5;
    const int p = p0 + tx;
    const int L = p % 12;
    const int H = c0 >> 6;                      // 32-channel tile stays in one head
    const long mbase = (((long)(b * 8 + H)) * 12 + L) * W4 + p - L;
    float mv[12];
    #pragma unroll
    for (int l = 0; l < 12; l++) mv[l] = Mw[mbase + l];
    #pragma unroll
    for (int r = 0; r < 4; r++) {
        const int  c   = c0 + ty + r * 8;
        const long row = (long)b * 512 + c;
        const long abase = row * W4 + p - L;
        float acc = 0.f;
        #pragma unroll
        for (int l = 0; l < 12; l++)
            acc += A2[abase + l] * mv[l];
        const long f = row * W4 + p;
        float x0 = (p > 0)      ? v0[f - 1] : 0.f;
        float x1 = v0[f];
        float x2 = (p < W4 - 1) ? v0[f + 1] : 0.f;
        acc += (x0 * pw[c * 3 + 0] + x1 * pw[c * 3 + 1] + x2 * pw[c * 3 + 2]) * pg[c] + pb[c];
        tile[ty + r * 8][tx] = acc;
    }
    __syncthreads();
    unsigned short* ohp = oh + ((long)b * W4 + p0) * 512 + c0;
    unsigned short* olp = ol + ((long)b * W4 + p0) * 512 + c0;
    #pragma unroll
    for (int r = 0; r < 4; r++) {
        float v = tile[tx][ty + r * 8];
        unsigned short h = f2bf(v);
        ohp[(long)(ty + r * 8) * 512 + tx] = h;
        olp[(long)(ty + r * 8) * 512 + tx] = f2bf(v - bf2f(h));
    }
}

// ---------------------------------------------------------------------------
extern "C" void kernel_launch(void* const* d_in, const int* in_sizes, int n_in,
                              void* d_out, int out_size, void* d_ws, size_t ws_size,
                              hipStream_t stream) {
    const float* x      = (const float*)d_in[0];
    const float* qk1_w  = (const float*)d_in[1];
    const float* qk1_g  = (const float*)d_in[2];
    const float* qk1_b  = (const float*)d_in[3];
    const float* qk2_w  = (const float*)d_in[4];
    const float* qk2_g  = (const float*)d_in[5];
    const float* qk2_b  = (const float*)d_in[6];
    const float* v_w    = (const float*)d_in[7];
    const float* v_g    = (const float*)d_in[8];
    const float* v_b    = (const float*)d_in[9];
    const float* pe_w   = (const float*)d_in[10];
    const float* pe_g   = (const float*)d_in[11];
    const float* pe_b   = (const float*)d_in[12];
    const float* proj_w = (const float*)d_in[13];
    const float* proj_g = (const float*)d_in[14];
    const float* proj_b = (const float*)d_in[15];
    float* out = (float*)d_out;

    char* ws = (char*)d_ws;
    size_t off = 0;
    auto alloc = [&](size_t bytes) -> void* {
        void* p = ws + off;
        off += (bytes + 255) & ~(size_t)255;
        return p;
    };
    const size_t QSZ = 4L * 256 * W4 * 4;   // 84,934,656 (= one fp16 xT plane too)
    const size_t KSZ = 4L * 32 * W4 * 4;    // 10,616,832
    const size_t WSZ = 4L * 96 * W4 * 4;    // 31,850,496
    const size_t ASZ = 4L * 512 * W4 * 4;   // 169,869,312

    ull*   opA   = (ull*)alloc(1152 * 8);
    int*   bsA   = (int*)alloc(1152 * 4);
    float* biasA = (float*)alloc(1152 * 4);
    ull*   opP   = (ull*)alloc(512 * 8);
    int*   bsP   = (int*)alloc(512 * 4);
    float* biasP = (float*)alloc(512 * 4);
    float* ksw1  = (float*)alloc(32 * 512 * 4);
    float* ksw2  = (float*)alloc(32 * 512 * 4);
    unsigned short* Waf = (unsigned short*)alloc(1152 * 512 * 2);
    unsigned short* Wph = (unsigned short*)alloc(512 * 512 * 2);
    unsigned short* Wpl = (unsigned short*)alloc(512 * 512 * 2);
    char*  RX  = (char*)alloc(2 * QSZ);     // xT fp16 / w2,w3,w4 / yT planes
    char*  RQ  = (char*)alloc(2 * QSZ);     // q1,q2 / A2
    float* ks1 = (float*)alloc(KSZ);
    float* ks2 = (float*)alloc(KSZ);
    float* w1  = (float*)alloc(WSZ);        // w1, later Mw
    float* A1  = (float*)alloc(ASZ);
    if (ws_size < off) return;              // ws known >= 606 MB; we use ~540 MB

    // region aliases (stream-ordered lifetimes; see launch sequence)
    unsigned short* xTf = (unsigned short*)RX;   // fp16 plane, QSZ bytes
    float* w2 = (float*)RX;                 // written after xTf is dead
    float* w3 = (float*)(RX + WSZ);
    float* w4 = (float*)(RX + 2 * WSZ);
    unsigned short* yTh = (unsigned short*)RX;  // written after w2-4 dead
    unsigned short* yTl = (unsigned short*)(RX + QSZ);
    float* q1 = (float*)RQ;
    float* q2 = (float*)(RQ + QSZ);
    float* A2 = (float*)RQ;                 // written after q1,q2 dead
    float* Mw = w1;                         // written after w1 dead

    // 1. tables + k-weight folds (fp32)
    prep1_kernel<<<66, 256, 0, stream>>>(
        qk1_w, qk1_g, qk1_b, qk2_w, qk2_g, qk2_b, v_b, proj_b,
        ksw1, ksw2, opA, bsA, biasA, opP, bsP, biasP,
        q1, q2, ks1, ks2, out);

    // 2. packed weight planes (fp16 for QKV, bf16 hi/lo for proj)
    prep2_kernel<<<1664, 256, 0, stream>>>(
        qk1_w, qk1_g, qk2_w, qk2_g, v_w, v_g, proj_w, proj_g,
        ksw1, ksw2, Waf, Wph, Wpl);

    // 3. x -> x^T fp16 plane
    castTf16_kernel<<<dim3(648, 16, 4), 256, 0, stream>>>(x, xTf);

    // 4. fused QKV GEMM (fp16 MFMA): q1,q2,v0(d_out),ks1,ks2
    mfma_gemm_f16<<<dim3(9, 162, 4), 256, 0, stream>>>(
        Waf, xTf, opA, bsA, biasA, 1088);

    // 5. a1 weights (axis i, stride 1728) + softmax
    logits12_kernel<<<dim3(81, 32), 256, 0, stream>>>(q1, ks1, w1, 1728);
    softmax_kernel<<<dim3(7, 12, 32), 256, 0, stream>>>(w1, 1728);

    // 6. apply a1: A1 = v0 (x) w1
    apply12_kernel<<<dim3(9, 2048), 192, 0, stream>>>(out, w1, A1, 1728);

    // 7. a2/a3/a4 weights (axes j/k/l) in one pass + softmaxes
    logits3_kernel<<<dim3(81, 32), 256, 0, stream>>>(q2, ks2, w2, w3, w4);
    softmax_kernel<<<dim3(7, 12, 32), 256, 0, stream>>>(w2, 144);
    softmax_kernel<<<dim3(7, 12, 32), 256, 0, stream>>>(w3, 12);
    softmax_kernel<<<dim3(7, 12, 32), 256, 0, stream>>>(w4, 1);

    // 8. M = sum_K a3*a4 (w3 register-cached, all 12 X per thread)
    mbuild12_kernel<<<dim3(81, 32), 256, 0, stream>>>(w3, w4, Mw);

    // 9. apply a2: A2 = A1 (x) w2
    apply12_kernel<<<dim3(9, 2048), 192, 0, stream>>>(A1, w2, A2, 144);

    // 10. fused y = (A2 (x) M) + pe(v0) -> y^T bf16 hi/lo planes
    fuse_y_kernel<<<dim3(648, 16, 4), 256, 0, stream>>>(
        A2, Mw, out, pe_w, pe_g, pe_b, yTh, yTl);

    // 11. proj GEMM (split-bf16, exact path) -> d_out
    mfma_gemm<<<dim3(4, 162, 4), 256, 0, stream>>>(
        Wph, Wpl, yTh, yTl, opP, bsP, biasP, 512);
}

// Round 4
// 1554.946 us; speedup vs baseline: 1.1557x; 1.1557x over previous
//
#include <hip/hip_runtime.h>
#include <hip/hip_bf16.h>
#include <stdint.h>

#define W4   20736           // 12^4 positions (w == W4, no padding)
#define NH   8
#define KD   32
#define HD   64
#define C    512
#define SCALE 0.17677669529663687f   // 1/sqrt(32)

typedef unsigned long long ull;
typedef short bf16x8 __attribute__((ext_vector_type(8)));
typedef _Float16 f16x8 __attribute__((ext_vector_type(8)));
typedef float f32x4 __attribute__((ext_vector_type(4)));

#define AS1(p) ((const __attribute__((address_space(1))) void*)(p))
#define AS3(p) ((__attribute__((address_space(3))) void*)(p))

// Manual RNE fp32 -> bf16 (no NaN handling needed; values finite)
static __device__ __forceinline__ unsigned short f2bf(float v) {
    unsigned u = __builtin_bit_cast(unsigned, v);
    unsigned r = u + 0x7FFF + ((u >> 16) & 1);
    return (unsigned short)(r >> 16);
}
static __device__ __forceinline__ float bf2f(unsigned short u) {
    unsigned x = ((unsigned)u) << 16;
    return __builtin_bit_cast(float, x);
}
// fp32 -> fp16 bits (RNE via v_cvt_f16_f32)
static __device__ __forceinline__ unsigned short f2h(float v) {
    return __builtin_bit_cast(unsigned short, (_Float16)v);
}

// ---------------------------------------------------------------------------
// prep1: fold head-summed K weights (fp32); build epilogue routing tables.
// ---------------------------------------------------------------------------
__global__ __launch_bounds__(256) void prep1_kernel(
    const float* qk1_w, const float* qk1_g, const float* qk1_b,
    const float* qk2_w, const float* qk2_g, const float* qk2_b,
    const float* v_b,   const float* proj_b,
    float* ksw1, float* ksw2,
    ull* opA, int* bsA, float* biasA,
    ull* opP, int* bsP, float* biasP,
    float* q1buf, float* q2buf, float* ks1buf, float* ks2buf, float* vdst)
{
    int z = blockIdx.x, t = threadIdx.x;
    if (z < 32) {                       // ksw1 row d=z : sum_h g*W over k1 channels
        int d = z;
        for (int c = t; c < 512; c += 256) {
            float a = 0.f;
            #pragma unroll
            for (int h = 0; h < 8; h++) {
                int ch = h * 64 + 32 + d;
                a += qk1_g[ch] * qk1_w[ch * 512 + c];
            }
            ksw1[d * 512 + c] = a;
        }
    } else if (z < 64) {                // ksw2 row d=z-32
        int d = z - 32;
        for (int c = t; c < 512; c += 256) {
            float a = 0.f;
            #pragma unroll
            for (int h = 0; h < 8; h++) {
                int ch = h * 64 + 32 + d;
                a += qk2_g[ch] * qk2_w[ch * 512 + c];
            }
            ksw2[d * 512 + c] = a;
        }
    } else if (z == 64) {               // table A: 1152 rows (1088 valid)
        for (int o = t; o < 1152; o += 256) {
            ull op; int bs; float bb;
            if (o < 256) {
                int ch = (o >> 5) * 64 + (o & 31);
                bb = qk1_b[ch];
                op = (ull)(uintptr_t)(q1buf + (size_t)o * W4); bs = 256 * W4;
            } else if (o < 512) {
                int oo = o - 256, ch = (oo >> 5) * 64 + (oo & 31);
                bb = qk2_b[ch];
                op = (ull)(uintptr_t)(q2buf + (size_t)oo * W4); bs = 256 * W4;
            } else if (o < 1024) {
                int c = o - 512;
                bb = v_b[c];
                op = (ull)(uintptr_t)(vdst + (size_t)c * W4); bs = 512 * W4;
            } else if (o < 1056) {
                int d = o - 1024; bb = 0.f;
                #pragma unroll
                for (int h = 0; h < 8; h++) bb += qk1_b[h * 64 + 32 + d];
                op = (ull)(uintptr_t)(ks1buf + (size_t)d * W4); bs = 32 * W4;
            } else if (o < 1088) {
                int d = o - 1056; bb = 0.f;
                #pragma unroll
                for (int h = 0; h < 8; h++) bb += qk2_b[h * 64 + 32 + d];
                op = (ull)(uintptr_t)(ks2buf + (size_t)d * W4); bs = 32 * W4;
            } else {                    // pad (masked by m_valid in epilogue)
                bb = 0.f; op = (ull)(uintptr_t)q1buf; bs = 0;
            }
            opA[o] = op; bsA[o] = bs; biasA[o] = bb;
        }
    } else {                            // table P (proj, 512 rows)
        for (int o = t; o < 512; o += 256) {
            opP[o] = (ull)(uintptr_t)(vdst + (size_t)o * W4);
            bsP[o] = 512 * W4;
            biasP[o] = proj_b[o];
        }
    }
}

// ---------------------------------------------------------------------------
// prep2: rows 0..1151 -> Waf fp16 (q1|q2|v|ks1|ks2|pad0, g folded);
// rows 1152..1663 -> Wph/Wpl bf16 hi/lo split (proj, exact path).
// ---------------------------------------------------------------------------
__global__ __launch_bounds__(256) void prep2_kernel(
    const float* qk1_w, const float* qk1_g,
    const float* qk2_w, const float* qk2_g,
    const float* v_w,   const float* v_g,
    const float* proj_w,const float* proj_g,
    const float* ksw1,  const float* ksw2,
    unsigned short* Waf,
    unsigned short* Wph, unsigned short* Wpl)
{
    int row = blockIdx.x, t = threadIdx.x;
    for (int c = t; c < 512; c += 256) {
        float wv;
        if (row < 1152) {
            int o = row;
            if (o < 256) {
                int ch = (o >> 5) * 64 + (o & 31);
                wv = qk1_w[ch * 512 + c] * qk1_g[ch];
            } else if (o < 512) {
                int oo = o - 256, ch = (oo >> 5) * 64 + (oo & 31);
                wv = qk2_w[ch * 512 + c] * qk2_g[ch];
            } else if (o < 1024) {
                int cc = o - 512;
                wv = v_w[cc * 512 + c] * v_g[cc];
            } else if (o < 1056) {
                wv = ksw1[(o - 1024) * 512 + c];
            } else if (o < 1088) {
                wv = ksw2[(o - 1056) * 512 + c];
            } else wv = 0.f;
            Waf[o * 512 + c] = f2h(wv);
        } else {
            int o = row - 1152;
            wv = proj_w[o * 512 + c] * proj_g[o];
            unsigned short h = f2bf(wv);
            Wph[o * 512 + c] = h;
            Wpl[o * 512 + c] = f2bf(wv - bf2f(h));
        }
    }
}

// ---------------------------------------------------------------------------
// castTf16: fp32 [b][512][W4] -> fp16 [b][W4][512] (transposed, single plane).
// 32x32 LDS tile transpose. Grid (648, 16, 4), block 256.
// ---------------------------------------------------------------------------
__global__ __launch_bounds__(256) void castTf16_kernel(
    const float* __restrict__ in, unsigned short* __restrict__ of)
{
    __shared__ float tile[32][33];
    const int p0 = blockIdx.x * 32, c0 = blockIdx.y * 32, b = blockIdx.z;
    const int tx = threadIdx.x & 31, ty = threadIdx.x >> 5;
    const float* ip = in + ((long)b * 512 + c0) * W4 + p0;
    #pragma unroll
    for (int r = 0; r < 4; r++)
        tile[ty + r * 8][tx] = ip[(long)(ty + r * 8) * W4 + tx];
    __syncthreads();
    unsigned short* ofp = of + ((long)b * W4 + p0) * 512 + c0;
    #pragma unroll
    for (int r = 0; r < 4; r++)
        ofp[(long)(ty + r * 8) * 512 + tx] = f2h(tile[tx][ty + r * 8]);
}

// ---------------------------------------------------------------------------
// mfma_gemm_f16: out[o,p] = A[o,:]·B[p,:] + bias[o], single fp16 MFMA.
// 128x128 tile, BK=32, 4 waves, 16x16x32 MFMA, m97 staging, XCD-chunk swizzle.
// ---------------------------------------------------------------------------
__global__ __launch_bounds__(256, 2) void mfma_gemm_f16(
    const unsigned short* __restrict__ Af,
    const unsigned short* __restrict__ Bf,
    const ull* __restrict__ outp, const int* __restrict__ obstr,
    const float* __restrict__ btab, int m_valid)
{
    __shared__ __align__(16) unsigned short sA[4096], sB[4096];
    const int t = threadIdx.x;
    const unsigned nx = gridDim.x, ny = gridDim.y;
    unsigned flat = blockIdx.x + nx * (blockIdx.y + ny * blockIdx.z);
    const unsigned cpx = (nx * ny * gridDim.z) >> 3;
    flat = (flat & 7u) * cpx + (flat >> 3);
    const int m0 = (int)(flat % nx) * 128;
    const int p0 = (int)((flat / nx) % ny) * 128;
    const int b  = (int)(flat / (nx * ny));
    const int lane = t & 63, wid = t >> 6;
    const int wm = wid >> 1, wn = wid & 1;
    const int r0 = t >> 2, part = (t & 3) * 8;
    const unsigned short* gA = Af + (size_t)(m0 + r0) * 512 + part;
    const unsigned short* gB = Bf + ((size_t)b * W4 + p0 + r0) * 512 + part;

    f32x4 acc[4][4];
    #pragma unroll
    for (int i = 0; i < 4; i++)
        #pragma unroll
        for (int j = 0; j < 4; j++) acc[i][j] = (f32x4)(0.f);

    const int arow = wm * 64 + (lane & 15);
    const int brow = wn * 64 + (lane & 15);
    const int koff = (lane >> 4) * 8;

    for (int k0 = 0; k0 < 512; k0 += 32) {
        __builtin_amdgcn_global_load_lds(AS1(gA + k0),          AS3((char*)sA + t * 16),        16, 0, 0);
        __builtin_amdgcn_global_load_lds(AS1(gA + 32768 + k0),  AS3((char*)sA + t * 16 + 4096), 16, 0, 0);
        __builtin_amdgcn_global_load_lds(AS1(gB + k0),          AS3((char*)sB + t * 16),        16, 0, 0);
        __builtin_amdgcn_global_load_lds(AS1(gB + 32768 + k0),  AS3((char*)sB + t * 16 + 4096), 16, 0, 0);
        __syncthreads();
        f16x8 a[4], bb[4];
        #pragma unroll
        for (int f = 0; f < 4; f++) {
            a[f]  = *(const f16x8*)(sA + (arow + f * 16) * 32 + koff);
            bb[f] = *(const f16x8*)(sB + (brow + f * 16) * 32 + koff);
        }
        #pragma unroll
        for (int i = 0; i < 4; i++)
            #pragma unroll
            for (int j = 0; j < 4; j++)
                acc[i][j] = __builtin_amdgcn_mfma_f32_16x16x32_f16(a[i], bb[j], acc[i][j], 0, 0, 0);
        __syncthreads();
    }
    const int quad = lane >> 4, col = lane & 15;
    #pragma unroll
    for (int i = 0; i < 4; i++) {
        #pragma unroll
        for (int r = 0; r < 4; r++) {
            int o = m0 + wm * 64 + i * 16 + quad * 4 + r;
            if (o >= m_valid) continue;
            float bias = btab[o];
            float* op = (float*)(uintptr_t)outp[o] + (long)b * obstr[o] + p0 + wn * 64 + col;
            #pragma unroll
            for (int j = 0; j < 4; j++)
                op[j * 16] = acc[i][j][r] + bias;
        }
    }
}

// ---------------------------------------------------------------------------
// mfma_gemm: split-bf16 (3 MFMA / tile) — kept for the proj GEMM (exact path).
// ---------------------------------------------------------------------------
__global__ __launch_bounds__(256, 2) void mfma_gemm(
    const unsigned short* __restrict__ Ah, const unsigned short* __restrict__ Al,
    const unsigned short* __restrict__ Bh, const unsigned short* __restrict__ Bl,
    const ull* __restrict__ outp, const int* __restrict__ obstr,
    const float* __restrict__ btab, int m_valid)
{
    __shared__ __align__(16) unsigned short sAh[4096], sAl[4096], sBh[4096], sBl[4096];
    const int t = threadIdx.x;
    const unsigned nx = gridDim.x, ny = gridDim.y;
    unsigned flat = blockIdx.x + nx * (blockIdx.y + ny * blockIdx.z);
    const unsigned cpx = (nx * ny * gridDim.z) >> 3;
    flat = (flat & 7u) * cpx + (flat >> 3);
    const int m0 = (int)(flat % nx) * 128;
    const int p0 = (int)((flat / nx) % ny) * 128;
    const int b  = (int)(flat / (nx * ny));
    const int lane = t & 63, wid = t >> 6;
    const int wm = wid >> 1, wn = wid & 1;
    const int r0 = t >> 2, part = (t & 3) * 8;
    const unsigned short* gAh = Ah + (size_t)(m0 + r0) * 512 + part;
    const unsigned short* gAl = Al + (size_t)(m0 + r0) * 512 + part;
    const unsigned short* gBh = Bh + ((size_t)b * W4 + p0 + r0) * 512 + part;
    const unsigned short* gBl = Bl + ((size_t)b * W4 + p0 + r0) * 512 + part;

    f32x4 acc[4][4];
    #pragma unroll
    for (int i = 0; i < 4; i++)
        #pragma unroll
        for (int j = 0; j < 4; j++) acc[i][j] = (f32x4)(0.f);

    const int arow = wm * 64 + (lane & 15);
    const int brow = wn * 64 + (lane & 15);
    const int koff = (lane >> 4) * 8;

    for (int k0 = 0; k0 < 512; k0 += 32) {
        __builtin_amdgcn_global_load_lds(AS1(gAh + k0),          AS3((char*)sAh + t * 16),        16, 0, 0);
        __builtin_amdgcn_global_load_lds(AS1(gAh + 32768 + k0),  AS3((char*)sAh + t * 16 + 4096), 16, 0, 0);
        __builtin_amdgcn_global_load_lds(AS1(gAl + k0),          AS3((char*)sAl + t * 16),        16, 0, 0);
        __builtin_amdgcn_global_load_lds(AS1(gAl + 32768 + k0),  AS3((char*)sAl + t * 16 + 4096), 16, 0, 0);
        __builtin_amdgcn_global_load_lds(AS1(gBh + k0),          AS3((char*)sBh + t * 16),        16, 0, 0);
        __builtin_amdgcn_global_load_lds(AS1(gBh + 32768 + k0),  AS3((char*)sBh + t * 16 + 4096), 16, 0, 0);
        __builtin_amdgcn_global_load_lds(AS1(gBl + k0),          AS3((char*)sBl + t * 16),        16, 0, 0);
        __builtin_amdgcn_global_load_lds(AS1(gBl + 32768 + k0),  AS3((char*)sBl + t * 16 + 4096), 16, 0, 0);
        __syncthreads();
        bf16x8 ah[4], al[4], bh[4], bl[4];
        #pragma unroll
        for (int f = 0; f < 4; f++) {
            ah[f] = *(const bf16x8*)(sAh + (arow + f * 16) * 32 + koff);
            al[f] = *(const bf16x8*)(sAl + (arow + f * 16) * 32 + koff);
            bh[f] = *(const bf16x8*)(sBh + (brow + f * 16) * 32 + koff);
            bl[f] = *(const bf16x8*)(sBl + (brow + f * 16) * 32 + koff);
        }
        #pragma unroll
        for (int i = 0; i < 4; i++)
            #pragma unroll
            for (int j = 0; j < 4; j++) {
                acc[i][j] = __builtin_amdgcn_mfma_f32_16x16x32_bf16(ah[i], bh[j], acc[i][j], 0, 0, 0);
                acc[i][j] = __builtin_amdgcn_mfma_f32_16x16x32_bf16(ah[i], bl[j], acc[i][j], 0, 0, 0);
                acc[i][j] = __builtin_amdgcn_mfma_f32_16x16x32_bf16(al[i], bh[j], acc[i][j], 0, 0, 0);
            }
        __syncthreads();
    }
    const int quad = lane >> 4, col = lane & 15;
    #pragma unroll
    for (int i = 0; i < 4; i++) {
        #pragma unroll
        for (int r = 0; r < 4; r++) {
            int o = m0 + wm * 64 + i * 16 + quad * 4 + r;
            if (o >= m_valid) continue;
            float bias = btab[o];
            float* op = (float*)(uintptr_t)outp[o] + (long)b * obstr[o] + p0 + wn * 64 + col;
            #pragma unroll
            for (int j = 0; j < 4; j++)
                op[j * 16] = acc[i][j][r] + bias;
        }
    }
}

// ---------------------------------------------------------------------------
// logits12: all 12 T per thread (q read once).
// ---------------------------------------------------------------------------
__global__ __launch_bounds__(256) void logits12_kernel(
    const float* __restrict__ q, const float* __restrict__ ks,
    float* __restrict__ w, int stride)
{
    const int bh = blockIdx.y, b = bh >> 3, H = bh & 7;
    const int p = blockIdx.x * 256 + threadIdx.x;
    const int ip = (p / stride) % 12;
    const float* qp = q + ((long)(b * 256 + H * 32)) * W4 + p;
    const float* kp = ks + ((long)(b * 32)) * W4 + p - (long)ip * stride;
    float acc[12];
    #pragma unroll
    for (int T = 0; T < 12; T++) acc[T] = 0.f;
    for (int d = 0; d < 32; d++) {
        float qv = qp[(long)d * W4];
        #pragma unroll
        for (int T = 0; T < 12; T++)
            acc[T] += qv * kp[(long)d * W4 + (long)T * stride];
    }
    #pragma unroll
    for (int T = 0; T < 12; T++)
        w[((long)bh * 12 + T) * W4 + p] = acc[T] * SCALE;
}

// ---------------------------------------------------------------------------
// logits3: w2 (stride 144), w3 (stride 12), w4 (stride 1) in ONE pass over q2.
// ---------------------------------------------------------------------------
__global__ __launch_bounds__(256) void logits3_kernel(
    const float* __restrict__ q, const float* __restrict__ ks,
    float* __restrict__ w2, float* __restrict__ w3, float* __restrict__ w4)
{
    const int bh = blockIdx.y, b = bh >> 3, H = bh & 7;
    const int p = blockIdx.x * 256 + threadIdx.x;
    const int i2 = (p / 144) % 12, i3 = (p / 12) % 12, i4 = p % 12;
    const float* qp = q + ((long)(b * 256 + H * 32)) * W4 + p;
    const float* kb = ks + ((long)(b * 32)) * W4 + p;
    const float* k2 = kb - i2 * 144;
    const float* k3 = kb - i3 * 12;
    const float* k4 = kb - i4;
    float a2[12], a3[12], a4[12];
    #pragma unroll
    for (int T = 0; T < 12; T++) { a2[T] = 0.f; a3[T] = 0.f; a4[T] = 0.f; }
    for (int d = 0; d < 32; d++) {
        const long o = (long)d * W4;
        float qv = qp[o];
        #pragma unroll
        for (int T = 0; T < 12; T++) {
            a2[T] += qv * k2[o + T * 144];
            a3[T] += qv * k3[o + T * 12];
            a4[T] += qv * k4[o + T];
        }
    }
    #pragma unroll
    for (int T = 0; T < 12; T++) {
        const long wo = ((long)bh * 12 + T) * W4 + p;
        w2[wo] = a2[T] * SCALE;
        w3[wo] = a3[T] * SCALE;
        w4[wo] = a4[T] * SCALE;
    }
}

// softmax over the `stride` axis (12 entries) — verified round 2
__global__ __launch_bounds__(256) void softmax_kernel(float* w, int stride)
{
    const int bh = blockIdx.z, T = blockIdx.y;
    const int r = blockIdx.x * 256 + threadIdx.x;
    if (r >= 1728) return;
    const long base = ((long)bh * 12 + T) * W4
                    + (long)(r / stride) * (stride * 12) + (r % stride);
    float v[12], m = -1e30f;
    #pragma unroll
    for (int s = 0; s < 12; s++) { v[s] = w[base + (long)s * stride]; m = fmaxf(m, v[s]); }
    float sum = 0.f;
    #pragma unroll
    for (int s = 0; s < 12; s++) { v[s] = __expf(v[s] - m); sum += v[s]; }
    const float inv = 1.f / sum;
    #pragma unroll
    for (int s = 0; s < 12; s++) w[base + (long)s * stride] = v[s] * inv;
}

// ---------------------------------------------------------------------------
// apply12v: all 12 outputs along the contraction axis per thread, 4-wide
// float4 vectorized (ILP fix for the latency-bound scalar apply12).
// Thread owns 4 consecutive intra-period offsets; since stride % 4 == 0 for
// both call sites (1728, 144), a float4 never crosses a period boundary and
// all addresses are 16B-aligned. Per-element accumulation order over s is
// identical to the scalar version (bit-identical results).
// Grid (2048), block 448 (432 active = 1728/4 float4 slots per row).
// ---------------------------------------------------------------------------
__global__ __launch_bounds__(448) void apply12v_kernel(
    const float* __restrict__ in, const float* __restrict__ w,
    float* __restrict__ out, int stride)
{
    const long row = blockIdx.x;
    const int  b = (int)(row >> 9), c = (int)(row & 511), H = c >> 6;
    const int  t = threadIdx.x;
    if (t >= 432) return;
    const int  idx = t * 4;                               // [0, 1728)
    const int  g = idx / stride;                          // 0 when stride==1728
    const int  u = idx - g * stride;
    const long pbase = (long)g * stride * 12 + u;
    const float* ip = in + row * W4 + pbase;
    const float* wp = w + ((long)(b * 8 + H) * 12) * W4 + pbase;
    float* op = out + row * W4 + pbase;
    f32x4 vin[12];
    #pragma unroll
    for (int s = 0; s < 12; s++)
        vin[s] = *(const f32x4*)(ip + (long)s * stride);
    #pragma unroll
    for (int T = 0; T < 12; T++) {
        const float* wT = wp + (long)T * W4;
        f32x4 wv[12];
        #pragma unroll
        for (int s = 0; s < 12; s++)
            wv[s] = *(const f32x4*)(wT + (long)s * stride);
        f32x4 acc = (f32x4)(0.f);
        #pragma unroll
        for (int s = 0; s < 12; s++)
            acc += vin[s] * wv[s];
        *(f32x4*)(op + (long)T * stride) = acc;
    }
}

// ---------------------------------------------------------------------------
// mbuild12: all 12 X per thread; w3 K-column register-cached (read once).
//   M[bh,X,p] = sum_K w3[bh,K,p] * w4[bh,X, p-kp*12 + K*12],  kp=(p/12)%12
// Grid (81, 32), block 256. Bit-identical accumulation order vs mbuild.
// ---------------------------------------------------------------------------
__global__ __launch_bounds__(256) void mbuild12_kernel(
    const float* __restrict__ w3, const float* __restrict__ w4,
    float* __restrict__ Mw)
{
    const int bh = blockIdx.y;
    const int p = blockIdx.x * 256 + threadIdx.x;
    const int kp = (p / 12) % 12;
    const long b3 = ((long)bh * 12) * W4 + p;
    float v3[12];
    #pragma unroll
    for (int K = 0; K < 12; K++) v3[K] = w3[b3 + (long)K * W4];
    const long b4r = ((long)bh * 12) * W4 + p - kp * 12;
    #pragma unroll
    for (int X = 0; X < 12; X++) {
        const float* w4X = w4 + b4r + (long)X * W4;
        float acc = 0.f;
        #pragma unroll
        for (int K = 0; K < 12; K++)
            acc += v3[K] * w4X[K * 12];
        Mw[((long)bh * 12 + X) * W4 + p] = acc;
    }
}

// ---------------------------------------------------------------------------
// fuse_y: y = (A2 ⊗ M) + pe(v0) -> transposed bf16 hi/lo planes (proj input).
// ---------------------------------------------------------------------------
__global__ __launch_bounds__(256) void fuse_y_kernel(
    const float* __restrict__ A2, const float* __restrict__ Mw,
    const float* __restrict__ v0,
    const float* __restrict__ pw, const float* __restrict__ pg,
    const float* __restrict__ pb,
    unsigned short* __restrict__ oh, unsigned short* __restrict__ ol)
{
    __shared__ float tile[32][33];
    const int p0 = blockIdx.x * 32, c0 = blockIdx.y * 32, b = blockIdx.z;
    const int tx = threadIdx.x & 31, ty = threadIdx.x >> 5;
    const int p = p0 + tx;
    const int L = p % 12;
    const int H = c0 >> 6;                      // 32-channel tile stays in one head
    const long mbase = (((long)(b * 8 + H)) * 12 + L) * W4 + p - L;
    float mv[12];
    #pragma unroll
    for (int l = 0; l < 12; l++) mv[l] = Mw[mbase + l];
    #pragma unroll
    for (int r = 0; r < 4; r++) {
        const int  c   = c0 + ty + r * 8;
        const long row = (long)b * 512 + c;
        const long abase = row * W4 + p - L;
        float acc = 0.f;
        #pragma unroll
        for (int l = 0; l < 12; l++)
            acc += A2[abase + l] * mv[l];
        const long f = row * W4 + p;
        float x0 = (p > 0)      ? v0[f - 1] : 0.f;
        float x1 = v0[f];
        float x2 = (p < W4 - 1) ? v0[f + 1] : 0.f;
        acc += (x0 * pw[c * 3 + 0] + x1 * pw[c * 3 + 1] + x2 * pw[c * 3 + 2]) * pg[c] + pb[c];
        tile[ty + r * 8][tx] = acc;
    }
    __syncthreads();
    unsigned short* ohp = oh + ((long)b * W4 + p0) * 512 + c0;
    unsigned short* olp = ol + ((long)b * W4 + p0) * 512 + c0;
    #pragma unroll
    for (int r = 0; r < 4; r++) {
        float v = tile[tx][ty + r * 8];
        unsigned short h = f2bf(v);
        ohp[(long)(ty + r * 8) * 512 + tx] = h;
        olp[(long)(ty + r * 8) * 512 + tx] = f2bf(v - bf2f(h));
    }
}

// ---------------------------------------------------------------------------
extern "C" void kernel_launch(void* const* d_in, const int* in_sizes, int n_in,
                              void* d_out, int out_size, void* d_ws, size_t ws_size,
                              hipStream_t stream) {
    const float* x      = (const float*)d_in[0];
    const float* qk1_w  = (const float*)d_in[1];
    const float* qk1_g  = (const float*)d_in[2];
    const float* qk1_b  = (const float*)d_in[3];
    const float* qk2_w  = (const float*)d_in[4];
    const float* qk2_g  = (const float*)d_in[5];
    const float* qk2_b  = (const float*)d_in[6];
    const float* v_w    = (const float*)d_in[7];
    const float* v_g    = (const float*)d_in[8];
    const float* v_b    = (const float*)d_in[9];
    const float* pe_w   = (const float*)d_in[10];
    const float* pe_g   = (const float*)d_in[11];
    const float* pe_b   = (const float*)d_in[12];
    const float* proj_w = (const float*)d_in[13];
    const float* proj_g = (const float*)d_in[14];
    const float* proj_b = (const float*)d_in[15];
    float* out = (float*)d_out;

    char* ws = (char*)d_ws;
    size_t off = 0;
    auto alloc = [&](size_t bytes) -> void* {
        void* p = ws + off;
        off += (bytes + 255) & ~(size_t)255;
        return p;
    };
    const size_t QSZ = 4L * 256 * W4 * 4;   // 84,934,656 (= one fp16 xT plane too)
    const size_t KSZ = 4L * 32 * W4 * 4;    // 10,616,832
    const size_t WSZ = 4L * 96 * W4 * 4;    // 31,850,496
    const size_t ASZ = 4L * 512 * W4 * 4;   // 169,869,312

    ull*   opA   = (ull*)alloc(1152 * 8);
    int*   bsA   = (int*)alloc(1152 * 4);
    float* biasA = (float*)alloc(1152 * 4);
    ull*   opP   = (ull*)alloc(512 * 8);
    int*   bsP   = (int*)alloc(512 * 4);
    float* biasP = (float*)alloc(512 * 4);
    float* ksw1  = (float*)alloc(32 * 512 * 4);
    float* ksw2  = (float*)alloc(32 * 512 * 4);
    unsigned short* Waf = (unsigned short*)alloc(1152 * 512 * 2);
    unsigned short* Wph = (unsigned short*)alloc(512 * 512 * 2);
    unsigned short* Wpl = (unsigned short*)alloc(512 * 512 * 2);
    char*  RX  = (char*)alloc(2 * QSZ);     // xT fp16 / w2,w3,w4 / yT planes
    char*  RQ  = (char*)alloc(2 * QSZ);     // q1,q2 / A2
    float* ks1 = (float*)alloc(KSZ);
    float* ks2 = (float*)alloc(KSZ);
    float* w1  = (float*)alloc(WSZ);        // w1, later Mw
    float* A1  = (float*)alloc(ASZ);
    if (ws_size < off) return;              // ws known >= 606 MB; we use ~540 MB

    // region aliases (stream-ordered lifetimes; see launch sequence)
    unsigned short* xTf = (unsigned short*)RX;   // fp16 plane, QSZ bytes
    float* w2 = (float*)RX;                 // written after xTf is dead
    float* w3 = (float*)(RX + WSZ);
    float* w4 = (float*)(RX + 2 * WSZ);
    unsigned short* yTh = (unsigned short*)RX;  // written after w2-4 dead
    unsigned short* yTl = (unsigned short*)(RX + QSZ);
    float* q1 = (float*)RQ;
    float* q2 = (float*)(RQ + QSZ);
    float* A2 = (float*)RQ;                 // written after q1,q2 dead
    float* Mw = w1;                         // written after w1 dead

    // 1. tables + k-weight folds (fp32)
    prep1_kernel<<<66, 256, 0, stream>>>(
        qk1_w, qk1_g, qk1_b, qk2_w, qk2_g, qk2_b, v_b, proj_b,
        ksw1, ksw2, opA, bsA, biasA, opP, bsP, biasP,
        q1, q2, ks1, ks2, out);

    // 2. packed weight planes (fp16 for QKV, bf16 hi/lo for proj)
    prep2_kernel<<<1664, 256, 0, stream>>>(
        qk1_w, qk1_g, qk2_w, qk2_g, v_w, v_g, proj_w, proj_g,
        ksw1, ksw2, Waf, Wph, Wpl);

    // 3. x -> x^T fp16 plane
    castTf16_kernel<<<dim3(648, 16, 4), 256, 0, stream>>>(x, xTf);

    // 4. fused QKV GEMM (fp16 MFMA): q1,q2,v0(d_out),ks1,ks2
    mfma_gemm_f16<<<dim3(9, 162, 4), 256, 0, stream>>>(
        Waf, xTf, opA, bsA, biasA, 1088);

    // 5. a1 weights (axis i, stride 1728) + softmax
    logits12_kernel<<<dim3(81, 32), 256, 0, stream>>>(q1, ks1, w1, 1728);
    softmax_kernel<<<dim3(7, 12, 32), 256, 0, stream>>>(w1, 1728);

    // 6. apply a1: A1 = v0 (x) w1
    apply12v_kernel<<<2048, 448, 0, stream>>>(out, w1, A1, 1728);

    // 7. a2/a3/a4 weights (axes j/k/l) in one pass + softmaxes
    logits3_kernel<<<dim3(81, 32), 256, 0, stream>>>(q2, ks2, w2, w3, w4);
    softmax_kernel<<<dim3(7, 12, 32), 256, 0, stream>>>(w2, 144);
    softmax_kernel<<<dim3(7, 12, 32), 256, 0, stream>>>(w3, 12);
    softmax_kernel<<<dim3(7, 12, 32), 256, 0, stream>>>(w4, 1);

    // 8. M = sum_K a3*a4 (w3 register-cached, all 12 X per thread)
    mbuild12_kernel<<<dim3(81, 32), 256, 0, stream>>>(w3, w4, Mw);

    // 9. apply a2: A2 = A1 (x) w2
    apply12v_kernel<<<2048, 448, 0, stream>>>(A1, w2, A2, 144);

    // 10. fused y = (A2 (x) M) + pe(v0) -> y^T bf16 hi/lo planes
    fuse_y_kernel<<<dim3(648, 16, 4), 256, 0, stream>>>(
        A2, Mw, out, pe_w, pe_g, pe_b, yTh, yTl);

    // 11. proj GEMM (split-bf16, exact path) -> d_out
    mfma_gemm<<<dim3(4, 162, 4), 256, 0, stream>>>(
        Wph, Wpl, yTh, yTl, opP, bsP, biasP, 512);
}

// Round 5
// 1547.748 us; speedup vs baseline: 1.1611x; 1.0047x over previous
//
#include <hip/hip_runtime.h>
#include <hip/hip_bf16.h>
#include <stdint.h>

#define W4   20736           // 12^4 positions (w == W4, no padding)
#define NH   8
#define KD   32
#define HD   64
#define C    512
#define SCALE 0.17677669529663687f   // 1/sqrt(32)

typedef unsigned long long ull;
typedef short bf16x8 __attribute__((ext_vector_type(8)));
typedef _Float16 f16x8 __attribute__((ext_vector_type(8)));
typedef float f32x4 __attribute__((ext_vector_type(4)));
typedef unsigned short u16x4 __attribute__((ext_vector_type(4)));

#define AS1(p) ((const __attribute__((address_space(1))) void*)(p))
#define AS3(p) ((__attribute__((address_space(3))) void*)(p))

// Manual RNE fp32 -> bf16 (no NaN handling needed; values finite)
static __device__ __forceinline__ unsigned short f2bf(float v) {
    unsigned u = __builtin_bit_cast(unsigned, v);
    unsigned r = u + 0x7FFF + ((u >> 16) & 1);
    return (unsigned short)(r >> 16);
}
static __device__ __forceinline__ float bf2f(unsigned short u) {
    unsigned x = ((unsigned)u) << 16;
    return __builtin_bit_cast(float, x);
}
// fp32 -> fp16 bits (RNE via v_cvt_f16_f32)
static __device__ __forceinline__ unsigned short f2h(float v) {
    return __builtin_bit_cast(unsigned short, (_Float16)v);
}

// ---------------------------------------------------------------------------
// prep1: fold head-summed K weights (fp32); build epilogue routing tables.
// ---------------------------------------------------------------------------
__global__ __launch_bounds__(256) void prep1_kernel(
    const float* qk1_w, const float* qk1_g, const float* qk1_b,
    const float* qk2_w, const float* qk2_g, const float* qk2_b,
    const float* v_b,   const float* proj_b,
    float* ksw1, float* ksw2,
    ull* opA, int* bsA, float* biasA,
    ull* opP, int* bsP, float* biasP,
    float* q1buf, float* q2buf, float* ks1buf, float* ks2buf, float* vdst)
{
    int z = blockIdx.x, t = threadIdx.x;
    if (z < 32) {                       // ksw1 row d=z : sum_h g*W over k1 channels
        int d = z;
        for (int c = t; c < 512; c += 256) {
            float a = 0.f;
            #pragma unroll
            for (int h = 0; h < 8; h++) {
                int ch = h * 64 + 32 + d;
                a += qk1_g[ch] * qk1_w[ch * 512 + c];
            }
            ksw1[d * 512 + c] = a;
        }
    } else if (z < 64) {                // ksw2 row d=z-32
        int d = z - 32;
        for (int c = t; c < 512; c += 256) {
            float a = 0.f;
            #pragma unroll
            for (int h = 0; h < 8; h++) {
                int ch = h * 64 + 32 + d;
                a += qk2_g[ch] * qk2_w[ch * 512 + c];
            }
            ksw2[d * 512 + c] = a;
        }
    } else if (z == 64) {               // table A: 1152 rows (1088 valid)
        for (int o = t; o < 1152; o += 256) {
            ull op; int bs; float bb;
            if (o < 256) {
                int ch = (o >> 5) * 64 + (o & 31);
                bb = qk1_b[ch];
                op = (ull)(uintptr_t)(q1buf + (size_t)o * W4); bs = 256 * W4;
            } else if (o < 512) {
                int oo = o - 256, ch = (oo >> 5) * 64 + (oo & 31);
                bb = qk2_b[ch];
                op = (ull)(uintptr_t)(q2buf + (size_t)oo * W4); bs = 256 * W4;
            } else if (o < 1024) {
                int c = o - 512;
                bb = v_b[c];
                op = (ull)(uintptr_t)(vdst + (size_t)c * W4); bs = 512 * W4;
            } else if (o < 1056) {
                int d = o - 1024; bb = 0.f;
                #pragma unroll
                for (int h = 0; h < 8; h++) bb += qk1_b[h * 64 + 32 + d];
                op = (ull)(uintptr_t)(ks1buf + (size_t)d * W4); bs = 32 * W4;
            } else if (o < 1088) {
                int d = o - 1056; bb = 0.f;
                #pragma unroll
                for (int h = 0; h < 8; h++) bb += qk2_b[h * 64 + 32 + d];
                op = (ull)(uintptr_t)(ks2buf + (size_t)d * W4); bs = 32 * W4;
            } else {                    // pad (masked by m_valid in epilogue)
                bb = 0.f; op = (ull)(uintptr_t)q1buf; bs = 0;
            }
            opA[o] = op; bsA[o] = bs; biasA[o] = bb;
        }
    } else {                            // table P (proj, 512 rows)
        for (int o = t; o < 512; o += 256) {
            opP[o] = (ull)(uintptr_t)(vdst + (size_t)o * W4);
            bsP[o] = 512 * W4;
            biasP[o] = proj_b[o];
        }
    }
}

// ---------------------------------------------------------------------------
// prep2: rows 0..1151 -> Waf fp16 (q1|q2|v|ks1|ks2|pad0, g folded);
// rows 1152..1663 -> Wph/Wpl bf16 hi/lo split (proj, exact path).
// ---------------------------------------------------------------------------
__global__ __launch_bounds__(256) void prep2_kernel(
    const float* qk1_w, const float* qk1_g,
    const float* qk2_w, const float* qk2_g,
    const float* v_w,   const float* v_g,
    const float* proj_w,const float* proj_g,
    const float* ksw1,  const float* ksw2,
    unsigned short* Waf,
    unsigned short* Wph, unsigned short* Wpl)
{
    int row = blockIdx.x, t = threadIdx.x;
    for (int c = t; c < 512; c += 256) {
        float wv;
        if (row < 1152) {
            int o = row;
            if (o < 256) {
                int ch = (o >> 5) * 64 + (o & 31);
                wv = qk1_w[ch * 512 + c] * qk1_g[ch];
            } else if (o < 512) {
                int oo = o - 256, ch = (oo >> 5) * 64 + (oo & 31);
                wv = qk2_w[ch * 512 + c] * qk2_g[ch];
            } else if (o < 1024) {
                int cc = o - 512;
                wv = v_w[cc * 512 + c] * v_g[cc];
            } else if (o < 1056) {
                wv = ksw1[(o - 1024) * 512 + c];
            } else if (o < 1088) {
                wv = ksw2[(o - 1056) * 512 + c];
            } else wv = 0.f;
            Waf[o * 512 + c] = f2h(wv);
        } else {
            int o = row - 1152;
            wv = proj_w[o * 512 + c] * proj_g[o];
            unsigned short h = f2bf(wv);
            Wph[o * 512 + c] = h;
            Wpl[o * 512 + c] = f2bf(wv - bf2f(h));
        }
    }
}

// ---------------------------------------------------------------------------
// castTf16: fp32 [b][512][W4] -> fp16 [b][W4][512] (transposed, single plane).
// 32x32 LDS tile transpose. Grid (648, 16, 4), block 256.
// ---------------------------------------------------------------------------
__global__ __launch_bounds__(256) void castTf16_kernel(
    const float* __restrict__ in, unsigned short* __restrict__ of)
{
    __shared__ float tile[32][33];
    const int p0 = blockIdx.x * 32, c0 = blockIdx.y * 32, b = blockIdx.z;
    const int tx = threadIdx.x & 31, ty = threadIdx.x >> 5;
    const float* ip = in + ((long)b * 512 + c0) * W4 + p0;
    #pragma unroll
    for (int r = 0; r < 4; r++)
        tile[ty + r * 8][tx] = ip[(long)(ty + r * 8) * W4 + tx];
    __syncthreads();
    unsigned short* ofp = of + ((long)b * W4 + p0) * 512 + c0;
    #pragma unroll
    for (int r = 0; r < 4; r++)
        ofp[(long)(ty + r * 8) * 512 + tx] = f2h(tile[tx][ty + r * 8]);
}

// ---------------------------------------------------------------------------
// mfma_gemm_f16: out[o,p] = A[o,:]·B[p,:] + bias[o], single fp16 MFMA.
// 128x128 tile, BK=32, 4 waves, 16x16x32 MFMA, m97 staging, XCD-chunk swizzle.
// ---------------------------------------------------------------------------
__global__ __launch_bounds__(256, 2) void mfma_gemm_f16(
    const unsigned short* __restrict__ Af,
    const unsigned short* __restrict__ Bf,
    const ull* __restrict__ outp, const int* __restrict__ obstr,
    const float* __restrict__ btab, int m_valid)
{
    __shared__ __align__(16) unsigned short sA[4096], sB[4096];
    const int t = threadIdx.x;
    const unsigned nx = gridDim.x, ny = gridDim.y;
    unsigned flat = blockIdx.x + nx * (blockIdx.y + ny * blockIdx.z);
    const unsigned cpx = (nx * ny * gridDim.z) >> 3;
    flat = (flat & 7u) * cpx + (flat >> 3);
    const int m0 = (int)(flat % nx) * 128;
    const int p0 = (int)((flat / nx) % ny) * 128;
    const int b  = (int)(flat / (nx * ny));
    const int lane = t & 63, wid = t >> 6;
    const int wm = wid >> 1, wn = wid & 1;
    const int r0 = t >> 2, part = (t & 3) * 8;
    const unsigned short* gA = Af + (size_t)(m0 + r0) * 512 + part;
    const unsigned short* gB = Bf + ((size_t)b * W4 + p0 + r0) * 512 + part;

    f32x4 acc[4][4];
    #pragma unroll
    for (int i = 0; i < 4; i++)
        #pragma unroll
        for (int j = 0; j < 4; j++) acc[i][j] = (f32x4)(0.f);

    const int arow = wm * 64 + (lane & 15);
    const int brow = wn * 64 + (lane & 15);
    const int koff = (lane >> 4) * 8;

    for (int k0 = 0; k0 < 512; k0 += 32) {
        __builtin_amdgcn_global_load_lds(AS1(gA + k0),          AS3((char*)sA + t * 16),        16, 0, 0);
        __builtin_amdgcn_global_load_lds(AS1(gA + 32768 + k0),  AS3((char*)sA + t * 16 + 4096), 16, 0, 0);
        __builtin_amdgcn_global_load_lds(AS1(gB + k0),          AS3((char*)sB + t * 16),        16, 0, 0);
        __builtin_amdgcn_global_load_lds(AS1(gB + 32768 + k0),  AS3((char*)sB + t * 16 + 4096), 16, 0, 0);
        __syncthreads();
        f16x8 a[4], bb[4];
        #pragma unroll
        for (int f = 0; f < 4; f++) {
            a[f]  = *(const f16x8*)(sA + (arow + f * 16) * 32 + koff);
            bb[f] = *(const f16x8*)(sB + (brow + f * 16) * 32 + koff);
        }
        #pragma unroll
        for (int i = 0; i < 4; i++)
            #pragma unroll
            for (int j = 0; j < 4; j++)
                acc[i][j] = __builtin_amdgcn_mfma_f32_16x16x32_f16(a[i], bb[j], acc[i][j], 0, 0, 0);
        __syncthreads();
    }
    const int quad = lane >> 4, col = lane & 15;
    #pragma unroll
    for (int i = 0; i < 4; i++) {
        #pragma unroll
        for (int r = 0; r < 4; r++) {
            int o = m0 + wm * 64 + i * 16 + quad * 4 + r;
            if (o >= m_valid) continue;
            float bias = btab[o];
            float* op = (float*)(uintptr_t)outp[o] + (long)b * obstr[o] + p0 + wn * 64 + col;
            #pragma unroll
            for (int j = 0; j < 4; j++)
                op[j * 16] = acc[i][j][r] + bias;
        }
    }
}

// ---------------------------------------------------------------------------
// mfma_gemm: split-bf16 (3 MFMA / tile) — kept for the proj GEMM (exact path).
// ---------------------------------------------------------------------------
__global__ __launch_bounds__(256, 2) void mfma_gemm(
    const unsigned short* __restrict__ Ah, const unsigned short* __restrict__ Al,
    const unsigned short* __restrict__ Bh, const unsigned short* __restrict__ Bl,
    const ull* __restrict__ outp, const int* __restrict__ obstr,
    const float* __restrict__ btab, int m_valid)
{
    __shared__ __align__(16) unsigned short sAh[4096], sAl[4096], sBh[4096], sBl[4096];
    const int t = threadIdx.x;
    const unsigned nx = gridDim.x, ny = gridDim.y;
    unsigned flat = blockIdx.x + nx * (blockIdx.y + ny * blockIdx.z);
    const unsigned cpx = (nx * ny * gridDim.z) >> 3;
    flat = (flat & 7u) * cpx + (flat >> 3);
    const int m0 = (int)(flat % nx) * 128;
    const int p0 = (int)((flat / nx) % ny) * 128;
    const int b  = (int)(flat / (nx * ny));
    const int lane = t & 63, wid = t >> 6;
    const int wm = wid >> 1, wn = wid & 1;
    const int r0 = t >> 2, part = (t & 3) * 8;
    const unsigned short* gAh = Ah + (size_t)(m0 + r0) * 512 + part;
    const unsigned short* gAl = Al + (size_t)(m0 + r0) * 512 + part;
    const unsigned short* gBh = Bh + ((size_t)b * W4 + p0 + r0) * 512 + part;
    const unsigned short* gBl = Bl + ((size_t)b * W4 + p0 + r0) * 512 + part;

    f32x4 acc[4][4];
    #pragma unroll
    for (int i = 0; i < 4; i++)
        #pragma unroll
        for (int j = 0; j < 4; j++) acc[i][j] = (f32x4)(0.f);

    const int arow = wm * 64 + (lane & 15);
    const int brow = wn * 64 + (lane & 15);
    const int koff = (lane >> 4) * 8;

    for (int k0 = 0; k0 < 512; k0 += 32) {
        __builtin_amdgcn_global_load_lds(AS1(gAh + k0),          AS3((char*)sAh + t * 16),        16, 0, 0);
        __builtin_amdgcn_global_load_lds(AS1(gAh + 32768 + k0),  AS3((char*)sAh + t * 16 + 4096), 16, 0, 0);
        __builtin_amdgcn_global_load_lds(AS1(gAl + k0),          AS3((char*)sAl + t * 16),        16, 0, 0);
        __builtin_amdgcn_global_load_lds(AS1(gAl + 32768 + k0),  AS3((char*)sAl + t * 16 + 4096), 16, 0, 0);
        __builtin_amdgcn_global_load_lds(AS1(gBh + k0),          AS3((char*)sBh + t * 16),        16, 0, 0);
        __builtin_amdgcn_global_load_lds(AS1(gBh + 32768 + k0),  AS3((char*)sBh + t * 16 + 4096), 16, 0, 0);
        __builtin_amdgcn_global_load_lds(AS1(gBl + k0),          AS3((char*)sBl + t * 16),        16, 0, 0);
        __builtin_amdgcn_global_load_lds(AS1(gBl + 32768 + k0),  AS3((char*)sBl + t * 16 + 4096), 16, 0, 0);
        __syncthreads();
        bf16x8 ah[4], al[4], bh[4], bl[4];
        #pragma unroll
        for (int f = 0; f < 4; f++) {
            ah[f] = *(const bf16x8*)(sAh + (arow + f * 16) * 32 + koff);
            al[f] = *(const bf16x8*)(sAl + (arow + f * 16) * 32 + koff);
            bh[f] = *(const bf16x8*)(sBh + (brow + f * 16) * 32 + koff);
            bl[f] = *(const bf16x8*)(sBl + (brow + f * 16) * 32 + koff);
        }
        #pragma unroll
        for (int i = 0; i < 4; i++)
            #pragma unroll
            for (int j = 0; j < 4; j++) {
                acc[i][j] = __builtin_amdgcn_mfma_f32_16x16x32_bf16(ah[i], bh[j], acc[i][j], 0, 0, 0);
                acc[i][j] = __builtin_amdgcn_mfma_f32_16x16x32_bf16(ah[i], bl[j], acc[i][j], 0, 0, 0);
                acc[i][j] = __builtin_amdgcn_mfma_f32_16x16x32_bf16(al[i], bh[j], acc[i][j], 0, 0, 0);
            }
        __syncthreads();
    }
    const int quad = lane >> 4, col = lane & 15;
    #pragma unroll
    for (int i = 0; i < 4; i++) {
        #pragma unroll
        for (int r = 0; r < 4; r++) {
            int o = m0 + wm * 64 + i * 16 + quad * 4 + r;
            if (o >= m_valid) continue;
            float bias = btab[o];
            float* op = (float*)(uintptr_t)outp[o] + (long)b * obstr[o] + p0 + wn * 64 + col;
            #pragma unroll
            for (int j = 0; j < 4; j++)
                op[j * 16] = acc[i][j][r] + bias;
        }
    }
}

// ---------------------------------------------------------------------------
// logits12: all 12 T per thread (q read once).
// ---------------------------------------------------------------------------
__global__ __launch_bounds__(256) void logits12_kernel(
    const float* __restrict__ q, const float* __restrict__ ks,
    float* __restrict__ w, int stride)
{
    const int bh = blockIdx.y, b = bh >> 3, H = bh & 7;
    const int p = blockIdx.x * 256 + threadIdx.x;
    const int ip = (p / stride) % 12;
    const float* qp = q + ((long)(b * 256 + H * 32)) * W4 + p;
    const float* kp = ks + ((long)(b * 32)) * W4 + p - (long)ip * stride;
    float acc[12];
    #pragma unroll
    for (int T = 0; T < 12; T++) acc[T] = 0.f;
    for (int d = 0; d < 32; d++) {
        float qv = qp[(long)d * W4];
        #pragma unroll
        for (int T = 0; T < 12; T++)
            acc[T] += qv * kp[(long)d * W4 + (long)T * stride];
    }
    #pragma unroll
    for (int T = 0; T < 12; T++)
        w[((long)bh * 12 + T) * W4 + p] = acc[T] * SCALE;
}

// ---------------------------------------------------------------------------
// logits3: w2 (stride 144), w3 (stride 12), w4 (stride 1) in ONE pass over q2.
// ---------------------------------------------------------------------------
__global__ __launch_bounds__(256) void logits3_kernel(
    const float* __restrict__ q, const float* __restrict__ ks,
    float* __restrict__ w2, float* __restrict__ w3, float* __restrict__ w4)
{
    const int bh = blockIdx.y, b = bh >> 3, H = bh & 7;
    const int p = blockIdx.x * 256 + threadIdx.x;
    const int i2 = (p / 144) % 12, i3 = (p / 12) % 12, i4 = p % 12;
    const float* qp = q + ((long)(b * 256 + H * 32)) * W4 + p;
    const float* kb = ks + ((long)(b * 32)) * W4 + p;
    const float* k2 = kb - i2 * 144;
    const float* k3 = kb - i3 * 12;
    const float* k4 = kb - i4;
    float a2[12], a3[12], a4[12];
    #pragma unroll
    for (int T = 0; T < 12; T++) { a2[T] = 0.f; a3[T] = 0.f; a4[T] = 0.f; }
    for (int d = 0; d < 32; d++) {
        const long o = (long)d * W4;
        float qv = qp[o];
        #pragma unroll
        for (int T = 0; T < 12; T++) {
            a2[T] += qv * k2[o + T * 144];
            a3[T] += qv * k3[o + T * 12];
            a4[T] += qv * k4[o + T];
        }
    }
    #pragma unroll
    for (int T = 0; T < 12; T++) {
        const long wo = ((long)bh * 12 + T) * W4 + p;
        w2[wo] = a2[T] * SCALE;
        w3[wo] = a3[T] * SCALE;
        w4[wo] = a4[T] * SCALE;
    }
}

// softmax over the `stride` axis (12 entries) — verified round 2
__global__ __launch_bounds__(256) void softmax_kernel(float* w, int stride)
{
    const int bh = blockIdx.z, T = blockIdx.y;
    const int r = blockIdx.x * 256 + threadIdx.x;
    if (r >= 1728) return;
    const long base = ((long)bh * 12 + T) * W4
                    + (long)(r / stride) * (stride * 12) + (r % stride);
    float v[12], m = -1e30f;
    #pragma unroll
    for (int s = 0; s < 12; s++) { v[s] = w[base + (long)s * stride]; m = fmaxf(m, v[s]); }
    float sum = 0.f;
    #pragma unroll
    for (int s = 0; s < 12; s++) { v[s] = __expf(v[s] - m); sum += v[s]; }
    const float inv = 1.f / sum;
    #pragma unroll
    for (int s = 0; s < 12; s++) w[base + (long)s * stride] = v[s] * inv;
}

// ---------------------------------------------------------------------------
// apply12v: all 12 outputs along the contraction axis per thread, 4-wide
// float4 vectorized. Grid (2048), block 448 (432 active).
// ---------------------------------------------------------------------------
__global__ __launch_bounds__(448) void apply12v_kernel(
    const float* __restrict__ in, const float* __restrict__ w,
    float* __restrict__ out, int stride)
{
    const long row = blockIdx.x;
    const int  b = (int)(row >> 9), c = (int)(row & 511), H = c >> 6;
    const int  t = threadIdx.x;
    if (t >= 432) return;
    const int  idx = t * 4;                               // [0, 1728)
    const int  g = idx / stride;                          // 0 when stride==1728
    const int  u = idx - g * stride;
    const long pbase = (long)g * stride * 12 + u;
    const float* ip = in + row * W4 + pbase;
    const float* wp = w + ((long)(b * 8 + H) * 12) * W4 + pbase;
    float* op = out + row * W4 + pbase;
    f32x4 vin[12];
    #pragma unroll
    for (int s = 0; s < 12; s++)
        vin[s] = *(const f32x4*)(ip + (long)s * stride);
    #pragma unroll
    for (int T = 0; T < 12; T++) {
        const float* wT = wp + (long)T * W4;
        f32x4 wv[12];
        #pragma unroll
        for (int s = 0; s < 12; s++)
            wv[s] = *(const f32x4*)(wT + (long)s * stride);
        f32x4 acc = (f32x4)(0.f);
        #pragma unroll
        for (int s = 0; s < 12; s++)
            acc += vin[s] * wv[s];
        *(f32x4*)(op + (long)T * stride) = acc;
    }
}

// ---------------------------------------------------------------------------
// mbuild12: all 12 X per thread; w3 K-column register-cached (read once).
// ---------------------------------------------------------------------------
__global__ __launch_bounds__(256) void mbuild12_kernel(
    const float* __restrict__ w3, const float* __restrict__ w4,
    float* __restrict__ Mw)
{
    const int bh = blockIdx.y;
    const int p = blockIdx.x * 256 + threadIdx.x;
    const int kp = (p / 12) % 12;
    const long b3 = ((long)bh * 12) * W4 + p;
    float v3[12];
    #pragma unroll
    for (int K = 0; K < 12; K++) v3[K] = w3[b3 + (long)K * W4];
    const long b4r = ((long)bh * 12) * W4 + p - kp * 12;
    #pragma unroll
    for (int X = 0; X < 12; X++) {
        const float* w4X = w4 + b4r + (long)X * W4;
        float acc = 0.f;
        #pragma unroll
        for (int K = 0; K < 12; K++)
            acc += v3[K] * w4X[K * 12];
        Mw[((long)bh * 12 + X) * W4 + p] = acc;
    }
}

// ---------------------------------------------------------------------------
// fuse_y: y = (A2 ⊗ M) + pe(v0) -> transposed bf16 hi/lo planes (proj input).
// 4-wide restructure: thread owns a 4-aligned position quad (always inside
// one 12-block since 12 = 3*4): A2 window = 3 float4, each of 4 M rows =
// 3 float4, v0 = 1 float4 + 2 edge scalars  (18 loads / 4 outputs vs 72
// scalar before). Transpose tile roles swapped so stores are ushort4 (8B).
// Per-output accumulation order over l unchanged. Grid (648, 16, 4), blk 256.
// ---------------------------------------------------------------------------
__global__ __launch_bounds__(256) void fuse_y_kernel(
    const float* __restrict__ A2, const float* __restrict__ Mw,
    const float* __restrict__ v0,
    const float* __restrict__ pw, const float* __restrict__ pg,
    const float* __restrict__ pb,
    unsigned short* __restrict__ oh, unsigned short* __restrict__ ol)
{
    __shared__ float tile[32][33];            // [p_local][c_local], 2-way max
    const int p0 = blockIdx.x * 32, c0 = blockIdx.y * 32, b = blockIdx.z;
    const int t = threadIdx.x;
    const int tx = t & 7, ty = t >> 3;        // tx: p-quad 0..7, ty: c-row 0..31
    const int c  = c0 + ty;
    const int H  = c0 >> 6;                   // 32-channel tile stays in one head
    const int pq = p0 + tx * 4;               // quad base (4-aligned)
    const int base = pq - pq % 12;            // 12-block base (16B aligned)
    const int L0 = pq - base;                 // in {0,4,8}; L0+3 <= 11
    const long row = (long)b * 512 + c;

    // A2 window (12 floats, read once per thread)
    const float* ap = A2 + row * W4 + base;
    f32x4 av[3];
    av[0] = *(const f32x4*)(ap);
    av[1] = *(const f32x4*)(ap + 4);
    av[2] = *(const f32x4*)(ap + 8);

    // v0 for the 3-tap pe conv on [pq, pq+4)
    const long f0 = row * W4 + pq;
    f32x4 v0q = *(const f32x4*)(v0 + f0);
    float vm = (pq > 0)       ? v0[f0 - 1] : 0.f;
    float vp = (pq + 4 < W4)  ? v0[f0 + 4] : 0.f;
    const float w0 = pw[c * 3 + 0], w1 = pw[c * 3 + 1], w2c = pw[c * 3 + 2];
    const float g = pg[c], bb = pb[c];

    const float* mrow = Mw + (((long)(b * 8 + H)) * 12 + L0) * W4 + base;
    #pragma unroll
    for (int j = 0; j < 4; j++) {             // p = pq + j, L = L0 + j
        const float* mp = mrow + (long)j * W4;
        f32x4 mv[3];
        mv[0] = *(const f32x4*)(mp);
        mv[1] = *(const f32x4*)(mp + 4);
        mv[2] = *(const f32x4*)(mp + 8);
        float acc = 0.f;
        #pragma unroll
        for (int l = 0; l < 12; l++)
            acc += av[l >> 2][l & 3] * mv[l >> 2][l & 3];
        float x0 = (j == 0) ? vm : v0q[(j - 1) & 3];
        float x1 = v0q[j];
        float x2 = (j == 3) ? vp : v0q[(j + 1) & 3];
        acc += (x0 * w0 + x1 * w1 + x2 * w2c) * g + bb;
        tile[tx * 4 + j][ty] = acc;
    }
    __syncthreads();
    // store: thread owns 1 p-row, 4 consecutive c -> ushort4 stores
    const int prow = t >> 3;                  // 0..31
    const int cg = (t & 7) * 4;               // 0,4,...,28
    u16x4 hv, lv;
    #pragma unroll
    for (int i = 0; i < 4; i++) {
        float v = tile[prow][cg + i];
        unsigned short h = f2bf(v);
        hv[i] = h;
        lv[i] = f2bf(v - bf2f(h));
    }
    *(u16x4*)(oh + ((long)b * W4 + p0 + prow) * 512 + c0 + cg) = hv;
    *(u16x4*)(ol + ((long)b * W4 + p0 + prow) * 512 + c0 + cg) = lv;
}

// ---------------------------------------------------------------------------
extern "C" void kernel_launch(void* const* d_in, const int* in_sizes, int n_in,
                              void* d_out, int out_size, void* d_ws, size_t ws_size,
                              hipStream_t stream) {
    const float* x      = (const float*)d_in[0];
    const float* qk1_w  = (const float*)d_in[1];
    const float* qk1_g  = (const float*)d_in[2];
    const float* qk1_b  = (const float*)d_in[3];
    const float* qk2_w  = (const float*)d_in[4];
    const float* qk2_g  = (const float*)d_in[5];
    const float* qk2_b  = (const float*)d_in[6];
    const float* v_w    = (const float*)d_in[7];
    const float* v_g    = (const float*)d_in[8];
    const float* v_b    = (const float*)d_in[9];
    const float* pe_w   = (const float*)d_in[10];
    const float* pe_g   = (const float*)d_in[11];
    const float* pe_b   = (const float*)d_in[12];
    const float* proj_w = (const float*)d_in[13];
    const float* proj_g = (const float*)d_in[14];
    const float* proj_b = (const float*)d_in[15];
    float* out = (float*)d_out;

    char* ws = (char*)d_ws;
    size_t off = 0;
    auto alloc = [&](size_t bytes) -> void* {
        void* p = ws + off;
        off += (bytes + 255) & ~(size_t)255;
        return p;
    };
    const size_t QSZ = 4L * 256 * W4 * 4;   // 84,934,656 (= one fp16 xT plane too)
    const size_t KSZ = 4L * 32 * W4 * 4;    // 10,616,832
    const size_t WSZ = 4L * 96 * W4 * 4;    // 31,850,496
    const size_t ASZ = 4L * 512 * W4 * 4;   // 169,869,312

    ull*   opA   = (ull*)alloc(1152 * 8);
    int*   bsA   = (int*)alloc(1152 * 4);
    float* biasA = (float*)alloc(1152 * 4);
    ull*   opP   = (ull*)alloc(512 * 8);
    int*   bsP   = (int*)alloc(512 * 4);
    float* biasP = (float*)alloc(512 * 4);
    float* ksw1  = (float*)alloc(32 * 512 * 4);
    float* ksw2  = (float*)alloc(32 * 512 * 4);
    unsigned short* Waf = (unsigned short*)alloc(1152 * 512 * 2);
    unsigned short* Wph = (unsigned short*)alloc(512 * 512 * 2);
    unsigned short* Wpl = (unsigned short*)alloc(512 * 512 * 2);
    char*  RX  = (char*)alloc(2 * QSZ);     // xT fp16 / w2,w3,w4 / yT planes
    char*  RQ  = (char*)alloc(2 * QSZ);     // q1,q2 / A2
    float* ks1 = (float*)alloc(KSZ);
    float* ks2 = (float*)alloc(KSZ);
    float* w1  = (float*)alloc(WSZ);        // w1, later Mw
    float* A1  = (float*)alloc(ASZ);
    if (ws_size < off) return;              // ws known >= 606 MB; we use ~540 MB

    // region aliases (stream-ordered lifetimes; see launch sequence)
    unsigned short* xTf = (unsigned short*)RX;   // fp16 plane, QSZ bytes
    float* w2 = (float*)RX;                 // written after xTf is dead
    float* w3 = (float*)(RX + WSZ);
    float* w4 = (float*)(RX + 2 * WSZ);
    unsigned short* yTh = (unsigned short*)RX;  // written after w2-4 dead
    unsigned short* yTl = (unsigned short*)(RX + QSZ);
    float* q1 = (float*)RQ;
    float* q2 = (float*)(RQ + QSZ);
    float* A2 = (float*)RQ;                 // written after q1,q2 dead
    float* Mw = w1;                         // written after w1 dead

    // 1. tables + k-weight folds (fp32)
    prep1_kernel<<<66, 256, 0, stream>>>(
        qk1_w, qk1_g, qk1_b, qk2_w, qk2_g, qk2_b, v_b, proj_b,
        ksw1, ksw2, opA, bsA, biasA, opP, bsP, biasP,
        q1, q2, ks1, ks2, out);

    // 2. packed weight planes (fp16 for QKV, bf16 hi/lo for proj)
    prep2_kernel<<<1664, 256, 0, stream>>>(
        qk1_w, qk1_g, qk2_w, qk2_g, v_w, v_g, proj_w, proj_g,
        ksw1, ksw2, Waf, Wph, Wpl);

    // 3. x -> x^T fp16 plane
    castTf16_kernel<<<dim3(648, 16, 4), 256, 0, stream>>>(x, xTf);

    // 4. fused QKV GEMM (fp16 MFMA): q1,q2,v0(d_out),ks1,ks2
    mfma_gemm_f16<<<dim3(9, 162, 4), 256, 0, stream>>>(
        Waf, xTf, opA, bsA, biasA, 1088);

    // 5. a1 weights (axis i, stride 1728) + softmax
    logits12_kernel<<<dim3(81, 32), 256, 0, stream>>>(q1, ks1, w1, 1728);
    softmax_kernel<<<dim3(7, 12, 32), 256, 0, stream>>>(w1, 1728);

    // 6. apply a1: A1 = v0 (x) w1
    apply12v_kernel<<<2048, 448, 0, stream>>>(out, w1, A1, 1728);

    // 7. a2/a3/a4 weights (axes j/k/l) in one pass + softmaxes
    logits3_kernel<<<dim3(81, 32), 256, 0, stream>>>(q2, ks2, w2, w3, w4);
    softmax_kernel<<<dim3(7, 12, 32), 256, 0, stream>>>(w2, 144);
    softmax_kernel<<<dim3(7, 12, 32), 256, 0, stream>>>(w3, 12);
    softmax_kernel<<<dim3(7, 12, 32), 256, 0, stream>>>(w4, 1);

    // 8. M = sum_K a3*a4 (w3 register-cached, all 12 X per thread)
    mbuild12_kernel<<<dim3(81, 32), 256, 0, stream>>>(w3, w4, Mw);

    // 9. apply a2: A2 = A1 (x) w2
    apply12v_kernel<<<2048, 448, 0, stream>>>(A1, w2, A2, 144);

    // 10. fused y = (A2 (x) M) + pe(v0) -> y^T bf16 hi/lo planes
    fuse_y_kernel<<<dim3(648, 16, 4), 256, 0, stream>>>(
        A2, Mw, out, pe_w, pe_g, pe_b, yTh, yTl);

    // 11. proj GEMM (split-bf16, exact path) -> d_out
    mfma_gemm<<<dim3(4, 162, 4), 256, 0, stream>>>(
        Wph, Wpl, yTh, yTl, opP, bsP, biasP, 512);
}